// Round 5
// baseline (1096.625 us; speedup 1.0000x reference)
//
#include <hip/hip_runtime.h>

#define NN 30000   // nodes
#define MMN 16     // neighbors
#define NF 1024    // input features
#define NC 16      // classes
#define KC 8       // capsules
#define DDIM 32    // dims per capsule
#define DR 256     // rep dim

typedef __bf16 bf16x8 __attribute__((ext_vector_type(8)));
typedef float floatx4 __attribute__((ext_vector_type(4)));

__device__ inline void splitbf(float v, __bf16& h, __bf16& l) {
  h = (__bf16)v;                 // RNE
  l = (__bf16)(v - (float)h);    // residual
}

// ---------------- wt_build: split-transpose w [1024,256] -> wt_hi/wt_lo [256,1024] bf16 ----------------
__global__ __launch_bounds__(256) void wt_build_kernel(
    const float* __restrict__ w, __bf16* __restrict__ wt_hi, __bf16* __restrict__ wt_lo) {
  const int gid = blockIdx.x * 256 + threadIdx.x;  // 32768 threads
  const int c  = gid >> 7;        // 0..255
  const int k0 = (gid & 127) << 3;
  bf16x8 h, l;
#pragma unroll
  for (int j = 0; j < 8; ++j) {
    const float v = w[(size_t)(k0 + j) * DR + c];
    __bf16 hh, ll; splitbf(v, hh, ll);
    h[j] = hh; l[j] = ll;
  }
  *(bf16x8*)(wt_hi + (size_t)c * NF + k0) = h;
  *(bf16x8*)(wt_lo + (size_t)c * NF + k0) = l;
}

// ---------------- pad_zero: zero the pad row of table B (256 floats) ----------------
__global__ void pad_zero_kernel(float* __restrict__ p) {
  ((float4*)p)[threadIdx.x] = make_float4(0.f, 0.f, 0.f, 0.f);  // 64 threads x 16B
}

// ---------------- PCA via split-bf16 MFMA: P = relu(x @ w + b) ----------------
__global__ __launch_bounds__(256) void pca_mfma_kernel(
    const float* __restrict__ x, const __bf16* __restrict__ wt_hi,
    const __bf16* __restrict__ wt_lo, const float* __restrict__ b,
    float* __restrict__ out) {
  __shared__ __bf16 Ah[128][40];
  __shared__ __bf16 Al[128][40];
  const int t    = threadIdx.x;
  const int lane = t & 63;
  const int wv   = t >> 6;
  const int q    = lane >> 4;
  const int lm   = lane & 15;
  const int rowBase = (blockIdx.x >> 2) << 7;
  const int colBase = (blockIdx.x & 3) << 6;

  const int sr = t >> 1;
  const int sk = (t & 1) << 4;

  floatx4 acc[2][4];
#pragma unroll
  for (int rt = 0; rt < 2; ++rt)
#pragma unroll
    for (int ct = 0; ct < 4; ++ct)
      acc[rt][ct] = (floatx4){0.f, 0.f, 0.f, 0.f};

  const float* xrow = x + (size_t)(rowBase + sr) * NF + sk;
  const bool srOK = (rowBase + sr) < NN;

  float4 xv[4];
  if (srOK) {
#pragma unroll
    for (int i = 0; i < 4; ++i) xv[i] = *(const float4*)(xrow + 4 * i);
  } else {
#pragma unroll
    for (int i = 0; i < 4; ++i) xv[i] = make_float4(0.f, 0.f, 0.f, 0.f);
  }

  for (int k0 = 0; k0 < NF; k0 += 32) {
    bf16x8 bh[4], bl[4];
#pragma unroll
    for (int ct = 0; ct < 4; ++ct) {
      const int n = colBase + (ct << 4) + lm;
      bh[ct] = *(const bf16x8*)(wt_hi + (size_t)n * NF + k0 + (q << 3));
      bl[ct] = *(const bf16x8*)(wt_lo + (size_t)n * NF + k0 + (q << 3));
    }
    __syncthreads();  // prior chunk's frag reads done before LDS overwrite
    {
      const float vs[16] = {xv[0].x, xv[0].y, xv[0].z, xv[0].w,
                            xv[1].x, xv[1].y, xv[1].z, xv[1].w,
                            xv[2].x, xv[2].y, xv[2].z, xv[2].w,
                            xv[3].x, xv[3].y, xv[3].z, xv[3].w};
      bf16x8 h0, l0, h1, l1;
#pragma unroll
      for (int j = 0; j < 8; ++j) { __bf16 H, L; splitbf(vs[j], H, L);     h0[j] = H; l0[j] = L; }
#pragma unroll
      for (int j = 0; j < 8; ++j) { __bf16 H, L; splitbf(vs[8 + j], H, L); h1[j] = H; l1[j] = L; }
      *(bf16x8*)&Ah[sr][sk]     = h0;
      *(bf16x8*)&Ah[sr][sk + 8] = h1;
      *(bf16x8*)&Al[sr][sk]     = l0;
      *(bf16x8*)&Al[sr][sk + 8] = l1;
    }
    // prefetch next x chunk — consumed after next barrier
    float4 xn[4];
    if (k0 + 32 < NF && srOK) {
#pragma unroll
      for (int i = 0; i < 4; ++i) xn[i] = *(const float4*)(xrow + k0 + 32 + 4 * i);
    } else {
#pragma unroll
      for (int i = 0; i < 4; ++i) xn[i] = make_float4(0.f, 0.f, 0.f, 0.f);
    }
    __syncthreads();
#pragma unroll
    for (int rt = 0; rt < 2; ++rt) {
      const int ar = (wv << 5) + (rt << 4) + lm;
      const bf16x8 ah = *(const bf16x8*)&Ah[ar][q << 3];
      const bf16x8 al = *(const bf16x8*)&Al[ar][q << 3];
#pragma unroll
      for (int ct = 0; ct < 4; ++ct) {
        acc[rt][ct] = __builtin_amdgcn_mfma_f32_16x16x32_bf16(ah, bh[ct], acc[rt][ct], 0, 0, 0);
        acc[rt][ct] = __builtin_amdgcn_mfma_f32_16x16x32_bf16(ah, bl[ct], acc[rt][ct], 0, 0, 0);
        acc[rt][ct] = __builtin_amdgcn_mfma_f32_16x16x32_bf16(al, bh[ct], acc[rt][ct], 0, 0, 0);
      }
    }
#pragma unroll
    for (int i = 0; i < 4; ++i) xv[i] = xn[i];
  }
  // epilogue: bias + relu; C/D layout col=lane&15, row=quad*4+reg
#pragma unroll
  for (int rt = 0; rt < 2; ++rt) {
#pragma unroll
    for (int ct = 0; ct < 4; ++ct) {
      const int col = colBase + (ct << 4) + lm;
      const float bias = b[col];
#pragma unroll
      for (int r = 0; r < 4; ++r) {
        const int row = rowBase + (wv << 5) + (rt << 4) + (q << 2) + r;
        if (row < NN) out[(size_t)row * DR + col] = fmaxf(acc[rt][ct][r] + bias, 0.f);
      }
    }
  }
}

// ---------- layer-0 normalize: Q = l2norm(relu(fc(l2norm(P)))) , pad row NN zeroed ----------
__global__ __launch_bounds__(256) void norm_fc_kernel(
    const float* __restrict__ hin, const float* __restrict__ fcw,
    const float* __restrict__ fcb, float* __restrict__ q) {
  const int gid = blockIdx.x * 256 + threadIdx.x;
  const int n = gid >> 3;
  const int k = gid & 7;
  if (n > NN) return;
  float* qrow = q + (size_t)n * DR + k * DDIM;
  if (n == NN) {
#pragma unroll
    for (int i = 0; i < DDIM; i += 4)
      *(float4*)(qrow + i) = make_float4(0.f, 0.f, 0.f, 0.f);
    return;
  }
  const float* hrow = hin + (size_t)n * DR + k * DDIM;
  float v[DDIM];
  float ss = 0.f;
#pragma unroll
  for (int i = 0; i < DDIM; i += 4) {
    float4 tv = *(const float4*)(hrow + i);
    tv.x = fmaxf(tv.x, 0.f); tv.y = fmaxf(tv.y, 0.f);
    tv.z = fmaxf(tv.z, 0.f); tv.w = fmaxf(tv.w, 0.f);
    v[i] = tv.x; v[i+1] = tv.y; v[i+2] = tv.z; v[i+3] = tv.w;
    ss += tv.x*tv.x + tv.y*tv.y + tv.z*tv.z + tv.w*tv.w;
  }
  float inv = 1.f / fmaxf(sqrtf(ss), 1e-12f);
#pragma unroll
  for (int i = 0; i < DDIM; ++i) v[i] *= inv;
  float y[DDIM];
  ss = 0.f;
  const float* wk = fcw + (size_t)k * DDIM * DDIM;
#pragma unroll 4
  for (int o = 0; o < DDIM; ++o) {
    float a = fcb[k * DDIM + o];
#pragma unroll
    for (int i = 0; i < DDIM; i += 4) {
      const float4 wv = *(const float4*)(wk + o * DDIM + i);
      a += v[i]*wv.x + v[i+1]*wv.y + v[i+2]*wv.z + v[i+3]*wv.w;
    }
    a = fmaxf(a, 0.f);
    y[o] = a;
    ss += a * a;
  }
  inv = 1.f / fmaxf(sqrtf(ss), 1e-12f);
#pragma unroll
  for (int o = 0; o < DDIM; o += 4) {
    float4 tv;
    tv.x = y[o]*inv; tv.y = y[o+1]*inv; tv.z = y[o+2]*inv; tv.w = y[o+3]*inv;
    *(float4*)(qrow + o) = tv;
  }
}

// ---------------- routing: wave per node, z PINNED in VGPRs ----------------
// The asm "+v" barrier makes z opaque: compiler cannot rematerialize it by
// re-loading from global inside the iter loop (R4: VGPR=52, FETCH=224MB/disp
// proved it was doing exactly that).
__global__ __launch_bounds__(256, 3) void routing_kernel(
    const float* __restrict__ tab, const float* __restrict__ padrow,
    const int* __restrict__ nbr, const float* __restrict__ rawp,
    const int* __restrict__ ritp, float* __restrict__ uout, const int doNorm) {
  const int lane = threadIdx.x & 63;
  const int node = blockIdx.x * 4 + (threadIdx.x >> 6);
  const int off = (lane >> 3) * DDIM + (lane & 7) * 4;
  const float param = 1.f / (1.f + __expf(-rawp[0]));
  const float qparam = 1.f - param;
  const int iters = ritp[0];

  float4 z[MMN];
#pragma unroll
  for (int m = 0; m < MMN; ++m) {
    const int j = nbr[node * MMN + m];                    // wave-uniform
    const float* zrow = (j == NN) ? padrow : (tab + (size_t)j * DR);
    z[m] = *(const float4*)(zrow + off);
  }
#pragma unroll
  for (int m = 0; m < MMN; ++m) {
    asm volatile("" : "+v"(z[m].x), "+v"(z[m].y), "+v"(z[m].z), "+v"(z[m].w));
  }
  float4 ub = *(const float4*)(tab + (size_t)node * DR + off);
  float4 u = ub;

  for (int it = 0; it < iters; ++it) {
    float e[MMN];  // exp(p[m]); no max-subtraction needed: |p|<=1 (unit-norm dots)
    if (it == 0) {
#pragma unroll
      for (int m = 0; m < MMN; ++m) e[m] = 1.f;
    } else {
#pragma unroll
      for (int m = 0; m < MMN; ++m) {
        float d = z[m].x*u.x + z[m].y*u.y + z[m].z*u.z + z[m].w*u.w;
        d += __shfl_xor(d, 1);
        d += __shfl_xor(d, 2);
        d += __shfl_xor(d, 4);
        e[m] = __expf(d);
      }
    }
    float sm = 0.f;
#pragma unroll
    for (int m = 0; m < MMN; ++m) sm += e[m];
    float sk[MMN];
#pragma unroll
    for (int m = 0; m < MMN; ++m) sk[m] = e[m];
#pragma unroll
    for (int m = 0; m < MMN; ++m) sk[m] += __shfl_xor(sk[m], 8);
#pragma unroll
    for (int m = 0; m < MMN; ++m) sk[m] += __shfl_xor(sk[m], 16);
#pragma unroll
    for (int m = 0; m < MMN; ++m) sk[m] += __shfl_xor(sk[m], 32);
    const float c1 = param * __builtin_amdgcn_rcpf(sm);
    float4 un = ub;
#pragma unroll
    for (int m = 0; m < MMN; ++m) {
      const float wm = e[m] * (c1 + qparam * __builtin_amdgcn_rcpf(sk[m]));
      un.x += wm*z[m].x; un.y += wm*z[m].y; un.z += wm*z[m].z; un.w += wm*z[m].w;
    }
    ub = un;
    if (it < iters - 1) {
      float ss = un.x*un.x + un.y*un.y + un.z*un.z + un.w*un.w;
      ss += __shfl_xor(ss, 1);
      ss += __shfl_xor(ss, 2);
      ss += __shfl_xor(ss, 4);
      const float inv = 1.f / fmaxf(sqrtf(ss), 1e-12f);
      u.x = un.x*inv; u.y = un.y*inv; u.z = un.z*inv; u.w = un.w*inv;
    } else {
      u = un;
    }
  }
  float4 w = ub;
  if (doNorm) {  // fused next-layer prep: l2norm(relu(u)) per capsule
    w.x = fmaxf(w.x, 0.f); w.y = fmaxf(w.y, 0.f);
    w.z = fmaxf(w.z, 0.f); w.w = fmaxf(w.w, 0.f);
    float ss = w.x*w.x + w.y*w.y + w.z*w.z + w.w*w.w;
    ss += __shfl_xor(ss, 1);
    ss += __shfl_xor(ss, 2);
    ss += __shfl_xor(ss, 4);
    const float inv = 1.f / fmaxf(sqrtf(ss), 1e-12f);
    w.x *= inv; w.y *= inv; w.z *= inv; w.w *= inv;
  }
  *(float4*)(uout + (size_t)node * DR + off) = w;
}

// ---------------- MLP head + log_softmax ----------------
__global__ __launch_bounds__(256) void mlp_kernel(
    const float* __restrict__ h, const float* __restrict__ w,
    const float* __restrict__ b, float* __restrict__ out) {
  const int lane = threadIdx.x & 63;
  const int node = blockIdx.x * 4 + (threadIdx.x >> 6);
  const int c  = lane >> 2;
  const int qq = lane & 3;
  const float* hrow = h + (size_t)node * DR + qq * 64;
  const float* wrow = w + (size_t)c * DR + qq * 64;
  float acc = 0.f;
#pragma unroll
  for (int i = 0; i < 64; i += 4) {
    const float4 hv = *(const float4*)(hrow + i);
    const float4 wv = *(const float4*)(wrow + i);
    acc += hv.x*wv.x + hv.y*wv.y + hv.z*wv.z + hv.w*wv.w;
  }
  acc += __shfl_xor(acc, 1);
  acc += __shfl_xor(acc, 2);
  const float logit = acc + b[c];
  float mx = logit;
  mx = fmaxf(mx, __shfl_xor(mx, 4));
  mx = fmaxf(mx, __shfl_xor(mx, 8));
  mx = fmaxf(mx, __shfl_xor(mx, 16));
  mx = fmaxf(mx, __shfl_xor(mx, 32));
  const float e = __expf(logit - mx);
  float se = e;
  se += __shfl_xor(se, 4);
  se += __shfl_xor(se, 8);
  se += __shfl_xor(se, 16);
  se += __shfl_xor(se, 32);
  const float lp = logit - mx - __logf(se);
  if (qq == 0) out[(size_t)node * NC + c] = lp;
}

extern "C" void kernel_launch(void* const* d_in, const int* in_sizes, int n_in,
                              void* d_out, int out_size, void* d_ws, size_t ws_size,
                              hipStream_t stream) {
  const float* x     = (const float*)d_in[0];
  const int*   nbr   = (const int*)  d_in[1];
  const float* pca_w = (const float*)d_in[2];
  const float* pca_b = (const float*)d_in[3];
  const float* rawp  = (const float*)d_in[4];
  const float* fc_w  = (const float*)d_in[5];
  const float* fc_b  = (const float*)d_in[6];
  const float* mlp_w = (const float*)d_in[7];
  const float* mlp_b = (const float*)d_in[8];
  const int*   ritp  = (const int*)  d_in[9];

  float* out  = (float*)d_out;                  // log_probs [NN,NC] then h [NN,DR]
  float* EMB  = out + (size_t)NN * NC;          // embedding region; also ping table B rows
  float* Bpad = EMB - DR;                       // table-B zero row (tail of log_probs region, dead until mlp)
  float* Q    = (float*)d_ws;                   // [NN+1, DR] table A (+pad row NN)
  float* Qpad = Q + (size_t)NN * DR;

  // wt scratch: first 1MB of log_probs region (disjoint from Bpad; dead until mlp)
  __bf16* wt_hi = (__bf16*)d_out;               // [256][1024]
  __bf16* wt_lo = wt_hi + (size_t)DR * NF;

  wt_build_kernel<<<128, 256, 0, stream>>>(pca_w, wt_hi, wt_lo);
  pad_zero_kernel<<<1, 64, 0, stream>>>(Bpad);
  // PCA + relu -> raw h rows at EMB
  pca_mfma_kernel<<<((NN + 127) / 128) * 4, 256, 0, stream>>>(x, wt_hi, wt_lo, pca_b, EMB);
  // layer 0 prep (per-capsule fc) -> Q
  norm_fc_kernel<<<((NN + 1) * KC + 255) / 256, 256, 0, stream>>>(EMB, fc_w, fc_b, Q);
  // L0: Q -> B (normalized epilogue)
  routing_kernel<<<NN / 4, 256, 0, stream>>>(Q, Qpad, nbr, rawp, ritp, EMB, 1);
  // L1: B -> Q (normalized epilogue)
  routing_kernel<<<NN / 4, 256, 0, stream>>>(EMB, Bpad, nbr, rawp, ritp, Q, 1);
  // L2: Q -> EMB raw (final embedding)
  routing_kernel<<<NN / 4, 256, 0, stream>>>(Q, Qpad, nbr, rawp, ritp, EMB, 0);
  // classifier head (overwrites wt scratch + Bpad with log_probs)
  mlp_kernel<<<NN / 4, 256, 0, stream>>>(EMB, mlp_w, mlp_b, out);
}